// Round 4
// baseline (314.349 us; speedup 1.0000x reference)
//
#include <hip/hip_runtime.h>
#include <hip/hip_bf16.h>

#define B_ 8
#define T_ 1024
#define IN_DIM_ 16
#define D_ 256
#define H_ 8
#define L_ 4
#define DK_ 32
#define BT_ (B_*T_)
#define LDT 72   // padded LDS stride for GEMM tiles (BK=64)
#define LDP 40   // padded LDS stride for attn P tile

typedef __attribute__((ext_vector_type(8))) __bf16 bf16x8;
typedef __attribute__((ext_vector_type(8))) unsigned short u16x8;
typedef __attribute__((ext_vector_type(4))) unsigned short u16x4;
typedef __attribute__((ext_vector_type(4))) float f32x4;

static __device__ __forceinline__ unsigned short f2bf(float f) {
  union { float f; unsigned int u; } c{f};
  unsigned int u = c.u;
  u += 0x7fff + ((u >> 16) & 1);
  return (unsigned short)(u >> 16);
}
static __device__ __forceinline__ bf16x8 as_bf(u16x8 v) {
  return __builtin_bit_cast(bf16x8, v);
}

// ---------------- weight prep: f32 [z][R][C] -> bf16 [z][C][R] ----------------
__global__ __launch_bounds__(256) void k_wprep(
    const float* __restrict__ in, unsigned short* __restrict__ out,
    int R, int C) {
  __shared__ float tile[64][65];
  const float* inz = in + (size_t)blockIdx.z * R * C;
  unsigned short* outz = out + (size_t)blockIdx.z * R * C;
  int r0 = blockIdx.y * 64, c0 = blockIdx.x * 64;
  int tid = threadIdx.x;
  int tr = tid >> 2, tc = (tid & 3) * 16;
  #pragma unroll
  for (int i = 0; i < 16; i += 4) {
    float4 v = *(const float4*)(inz + (r0 + tr) * C + c0 + tc + i);
    tile[tr][tc + i] = v.x; tile[tr][tc + i + 1] = v.y;
    tile[tr][tc + i + 2] = v.z; tile[tr][tc + i + 3] = v.w;
  }
  __syncthreads();
  #pragma unroll
  for (int i = 0; i < 16; ++i)
    outz[(c0 + tr) * R + r0 + tc + i] = f2bf(tile[tc + i][tr]);
}

// ---------------- input projection: h = x@Wp + bp + pos ----------------
__global__ __launch_bounds__(256) void k_proj(
    const float* __restrict__ x, const float* __restrict__ Wp,
    const float* __restrict__ bp, const float* __restrict__ pos,
    float* __restrict__ h, unsigned short* __restrict__ hbf) {
  int row = blockIdx.x;            // bt
  int c = threadIdx.x;             // 0..255
  int t = row & (T_ - 1);
  float acc = bp[c] + pos[t * D_ + c];
  const float* xr = x + row * IN_DIM_;
  #pragma unroll
  for (int k = 0; k < IN_DIM_; ++k) acc += xr[k] * Wp[k * D_ + c];
  h[row * D_ + c] = acc;
  hbf[row * D_ + c] = f2bf(acc);
}

// ---------------- QKV GEMM: (BTx256 bf16) x (768x256 bf16 W^T) ----------------
// q written PRE-SCALED by 1/sqrt(dk)*log2(e) -> attn does exp2(s) directly.
// q,k [b][h][t][dk]; v TRANSPOSED [b][h][dk][t]
__global__ __launch_bounds__(256) void k_gemm_qkv(
    const unsigned short* __restrict__ A,    // BT x 256 bf16
    const unsigned short* __restrict__ Bt,   // 768 x 256 bf16 (W^T)
    const float* __restrict__ bias,          // 768
    unsigned short* __restrict__ qb, unsigned short* __restrict__ kb,
    unsigned short* __restrict__ vt) {
  __shared__ unsigned short As[64 * LDT];
  __shared__ unsigned short Bs[64 * LDT];
  int row0 = blockIdx.x * 64;
  int col0 = blockIdx.y * 64;
  int tid = threadIdx.x;
  int lane = tid & 63, w = tid >> 6;
  int g = lane >> 4, li = lane & 15;
  int wr = (w >> 1) * 32, wc = (w & 1) * 32;
  f32x4 acc[2][2] = {};
  for (int k0 = 0; k0 < 256; k0 += 64) {
    __syncthreads();
    int r = tid >> 2, kk = (tid & 3) * 16;
    *(u16x8*)(As + r * LDT + kk)     = *(const u16x8*)(A + (row0 + r) * 256 + k0 + kk);
    *(u16x8*)(As + r * LDT + kk + 8) = *(const u16x8*)(A + (row0 + r) * 256 + k0 + kk + 8);
    *(u16x8*)(Bs + r * LDT + kk)     = *(const u16x8*)(Bt + (col0 + r) * 256 + k0 + kk);
    *(u16x8*)(Bs + r * LDT + kk + 8) = *(const u16x8*)(Bt + (col0 + r) * 256 + k0 + kk + 8);
    __syncthreads();
    #pragma unroll
    for (int ks = 0; ks < 2; ++ks) {
      bf16x8 af[2], bfr[2];
      #pragma unroll
      for (int m = 0; m < 2; ++m)
        af[m] = as_bf(*(const u16x8*)(As + (wr + m * 16 + li) * LDT + ks * 32 + g * 8));
      #pragma unroll
      for (int n = 0; n < 2; ++n)
        bfr[n] = as_bf(*(const u16x8*)(Bs + (wc + n * 16 + li) * LDT + ks * 32 + g * 8));
      #pragma unroll
      for (int m = 0; m < 2; ++m)
        #pragma unroll
        for (int n = 0; n < 2; ++n)
          acc[m][n] = __builtin_amdgcn_mfma_f32_16x16x32_bf16(af[m], bfr[n], acc[m][n], 0, 0, 0);
    }
  }
  const float QSC = 0.25505654f;  // (1/sqrt(32)) * log2(e)
  #pragma unroll
  for (int m = 0; m < 2; ++m)
    #pragma unroll
    for (int n = 0; n < 2; ++n) {
      int c = col0 + wc + n * 16 + li;
      int rbase = row0 + wr + m * 16 + g * 4;
      int b = rbase >> 10, t = rbase & (T_ - 1);
      int s = c >> 8, rem = c & 255, hh = rem >> 5, dk = rem & 31;
      if (s == 0) {
        #pragma unroll
        for (int j = 0; j < 4; ++j) {
          float v = (acc[m][n][j] + bias[c]) * QSC;
          qb[(((b * H_ + hh) * T_) + t + j) * DK_ + dk] = f2bf(v);
        }
      } else if (s == 1) {
        #pragma unroll
        for (int j = 0; j < 4; ++j) {
          float v = acc[m][n][j] + bias[c];
          kb[(((b * H_ + hh) * T_) + t + j) * DK_ + dk] = f2bf(v);
        }
      } else {
        u16x4 pk;
        #pragma unroll
        for (int j = 0; j < 4; ++j) pk[j] = f2bf(acc[m][n][j] + bias[c]);
        *(u16x4*)(vt + ((b * H_ + hh) * DK_ + dk) * T_ + t) = pk;
      }
    }
}

// ---------------- attention: split-K flash (2 waves / q-tile), no online max ----
// wave w handles k in [w*512,(w+1)*512); partial (O,l) are additive since no
// max-subtraction; combined via LDS at the end.
__global__ __launch_bounds__(128) void k_attn(
    const unsigned short* __restrict__ qb, const unsigned short* __restrict__ kb,
    const unsigned short* __restrict__ vt, unsigned short* __restrict__ ob) {
  __shared__ unsigned short P[2 * 16 * LDP];
  __shared__ float Osh[2][16][34];
  __shared__ float Lsh[2][16];
  int bh = blockIdx.y;
  int tid = threadIdx.x, lane = tid & 63, w = tid >> 6;  // w = k-half
  int g = lane >> 4, li = lane & 15;
  int q0 = blockIdx.x * 16;
  const unsigned short* Qp = qb + (bh * T_ + q0) * DK_;
  const unsigned short* Kp = kb + bh * T_ * DK_;
  const unsigned short* Vt = vt + bh * DK_ * T_;
  bf16x8 aq = as_bf(*(const u16x8*)(Qp + li * DK_ + g * 8));
  float l_run = 0.f;                         // lane-local partial denom (q = li)
  f32x4 oacc[2] = {};                        // O[q=g*4+j][dk=dh*16+li]
  unsigned short* Pw = P + w * 16 * LDP;
  for (int kt = w * 512; kt < (w + 1) * 512; kt += 32) {
    bf16x8 bk0 = as_bf(*(const u16x8*)(Kp + (kt + li) * DK_ + g * 8));
    bf16x8 bk1 = as_bf(*(const u16x8*)(Kp + (kt + 16 + li) * DK_ + g * 8));
    f32x4 s0 = {}, s1 = {};
    __builtin_amdgcn_s_setprio(1);
    // swapped: lane holds S[q=li][k=kt+g*4+j] (s0), +16 (s1); q pre-scaled
    s0 = __builtin_amdgcn_mfma_f32_16x16x32_bf16(bk0, aq, s0, 0, 0, 0);
    s1 = __builtin_amdgcn_mfma_f32_16x16x32_bf16(bk1, aq, s1, 0, 0, 0);
    __builtin_amdgcn_s_setprio(0);
    u16x4 w0, w1;
    float ps = 0.f;
    #pragma unroll
    for (int j = 0; j < 4; ++j) {
      float p0 = exp2f(s0[j]);
      float p1 = exp2f(s1[j]);
      ps += p0 + p1;
      w0[j] = f2bf(p0); w1[j] = f2bf(p1);
    }
    l_run += ps;
    *(u16x4*)(Pw + li * LDP + g * 4) = w0;
    *(u16x4*)(Pw + li * LDP + 16 + g * 4) = w1;
    // PV: A = P (ds_read_b128), B = V^T rows (vector global loads)
    bf16x8 pa = as_bf(*(const u16x8*)(Pw + li * LDP + g * 8));
    bf16x8 bv0 = as_bf(*(const u16x8*)(Vt + li * T_ + kt + g * 8));
    bf16x8 bv1 = as_bf(*(const u16x8*)(Vt + (16 + li) * T_ + kt + g * 8));
    __builtin_amdgcn_s_setprio(1);
    oacc[0] = __builtin_amdgcn_mfma_f32_16x16x32_bf16(pa, bv0, oacc[0], 0, 0, 0);
    oacc[1] = __builtin_amdgcn_mfma_f32_16x16x32_bf16(pa, bv1, oacc[1], 0, 0, 0);
    __builtin_amdgcn_s_setprio(0);
  }
  // reduce partial denominator across the 4 replicated groups
  l_run += __shfl_xor(l_run, 16);
  l_run += __shfl_xor(l_run, 32);
  // stash partials
  #pragma unroll
  for (int dh = 0; dh < 2; ++dh)
    #pragma unroll
    for (int j = 0; j < 4; ++j)
      Osh[w][g * 4 + j][dh * 16 + li] = oacc[dh][j];
  if (g == 0) Lsh[w][li] = l_run;
  __syncthreads();
  // combine halves; wave w writes dk-half w
  int b = bh >> 3, hh = bh & 7;
  #pragma unroll
  for (int j = 0; j < 4; ++j) {
    int q = g * 4 + j;
    int dk = w * 16 + li;
    float o = Osh[0][q][dk] + Osh[1][q][dk];
    float l = Lsh[0][q] + Lsh[1][q];
    ob[((b * T_ + q0 + q) * H_ + hh) * DK_ + dk] = f2bf(o / l);
  }
}

// ---------------- out-proj GEMM: o@Wout + bout + residual -> u (f32) ----------------
__global__ __launch_bounds__(256) void k_gemm_out(
    const unsigned short* __restrict__ A,    // BT x 256 bf16 (attn out)
    const unsigned short* __restrict__ Bt,   // 256 x 256 bf16 (W^T)
    const float* __restrict__ bias,          // 256
    const float* __restrict__ hres,          // BT x 256 f32 residual
    float* __restrict__ u) {
  __shared__ unsigned short As[64 * LDT];
  __shared__ unsigned short Bs[64 * LDT];
  int row0 = blockIdx.x * 64;
  int col0 = blockIdx.y * 64;
  int tid = threadIdx.x;
  int lane = tid & 63, w = tid >> 6;
  int g = lane >> 4, li = lane & 15;
  int wr = (w >> 1) * 32, wc = (w & 1) * 32;
  f32x4 acc[2][2] = {};
  for (int k0 = 0; k0 < 256; k0 += 64) {
    __syncthreads();
    int r = tid >> 2, kk = (tid & 3) * 16;
    *(u16x8*)(As + r * LDT + kk)     = *(const u16x8*)(A + (row0 + r) * 256 + k0 + kk);
    *(u16x8*)(As + r * LDT + kk + 8) = *(const u16x8*)(A + (row0 + r) * 256 + k0 + kk + 8);
    *(u16x8*)(Bs + r * LDT + kk)     = *(const u16x8*)(Bt + (col0 + r) * 256 + k0 + kk);
    *(u16x8*)(Bs + r * LDT + kk + 8) = *(const u16x8*)(Bt + (col0 + r) * 256 + k0 + kk + 8);
    __syncthreads();
    #pragma unroll
    for (int ks = 0; ks < 2; ++ks) {
      bf16x8 af[2], bfr[2];
      #pragma unroll
      for (int m = 0; m < 2; ++m)
        af[m] = as_bf(*(const u16x8*)(As + (wr + m * 16 + li) * LDT + ks * 32 + g * 8));
      #pragma unroll
      for (int n = 0; n < 2; ++n)
        bfr[n] = as_bf(*(const u16x8*)(Bs + (wc + n * 16 + li) * LDT + ks * 32 + g * 8));
      #pragma unroll
      for (int m = 0; m < 2; ++m)
        #pragma unroll
        for (int n = 0; n < 2; ++n)
          acc[m][n] = __builtin_amdgcn_mfma_f32_16x16x32_bf16(af[m], bfr[n], acc[m][n], 0, 0, 0);
    }
  }
  #pragma unroll
  for (int m = 0; m < 2; ++m)
    #pragma unroll
    for (int n = 0; n < 2; ++n)
      #pragma unroll
      for (int j = 0; j < 4; ++j) {
        int r = row0 + wr + m * 16 + g * 4 + j;
        int c = col0 + wc + n * 16 + li;
        u[r * 256 + c] = acc[m][n][j] + bias[c] + hres[r * 256 + c];
      }
}

// ---------------- layernorm: h = LN(u)*g + b; also bf16 mirror ----------------
__global__ __launch_bounds__(256) void k_ln(
    const float* __restrict__ u, const float* __restrict__ gg,
    const float* __restrict__ bb, float* __restrict__ h,
    unsigned short* __restrict__ hbf) {
  int row = blockIdx.x;
  int c = threadIdx.x;
  float v = u[row * D_ + c];
  float s = v, q = v * v;
  #pragma unroll
  for (int o = 1; o < 64; o <<= 1) { s += __shfl_xor(s, o); q += __shfl_xor(q, o); }
  __shared__ float ls[4], lq[4];
  int w = threadIdx.x >> 6;
  if ((threadIdx.x & 63) == 0) { ls[w] = s; lq[w] = q; }
  __syncthreads();
  s = ls[0] + ls[1] + ls[2] + ls[3];
  q = lq[0] + lq[1] + lq[2] + lq[3];
  float mean = s * (1.0f / D_);
  float var = q * (1.0f / D_) - mean * mean;
  float rstd = rsqrtf(var + 1e-5f);
  float y = (v - mean) * rstd * gg[c] + bb[c];
  h[row * D_ + c] = y;
  hbf[row * D_ + c] = f2bf(y);
}

// ---------------- final: out = h[:, -1, :] @ Wo + bo ----------------
__global__ void k_final(const float* __restrict__ h, const float* __restrict__ Wo,
                        const float* __restrict__ bo, float* __restrict__ out) {
  int tid = threadIdx.x;
  if (tid >= B_ * 3) return;
  int b = tid / 3, j = tid % 3;
  const float* hr = h + (b * T_ + (T_ - 1)) * D_;
  float acc = bo[j];
  for (int k = 0; k < D_; ++k) acc += hr[k] * Wo[k * 3 + j];
  out[tid] = acc;
}

extern "C" void kernel_launch(void* const* d_in, const int* in_sizes, int n_in,
                              void* d_out, int out_size, void* d_ws, size_t ws_size,
                              hipStream_t stream) {
  const float* x    = (const float*)d_in[0];
  const float* Wp   = (const float*)d_in[1];
  const float* bp   = (const float*)d_in[2];
  const float* pos  = (const float*)d_in[3];
  const float* Wqkv = (const float*)d_in[4];
  const float* bqkv = (const float*)d_in[5];
  const float* Wout = (const float*)d_in[6];
  const float* bout = (const float*)d_in[7];
  const float* ln_g = (const float*)d_in[8];
  const float* ln_b = (const float*)d_in[9];
  const float* Wo   = (const float*)d_in[10];
  const float* bo   = (const float*)d_in[11];

  char* ws = (char*)d_ws;
  float* h            = (float*)(ws);                        // 8 MB
  float* u            = (float*)(ws + (8u << 20));           // 8 MB
  unsigned short* hbf = (unsigned short*)(ws + (16u << 20)); // 4 MB
  unsigned short* qb  = (unsigned short*)(ws + (20u << 20)); // 4 MB
  unsigned short* kb  = (unsigned short*)(ws + (24u << 20)); // 4 MB
  unsigned short* vt  = (unsigned short*)(ws + (28u << 20)); // 4 MB (transposed V)
  unsigned short* ob  = (unsigned short*)(ws + (32u << 20)); // 4 MB
  unsigned short* WqkvT = (unsigned short*)(ws + (36u << 20)); // 1.5 MB
  unsigned short* WoutT = (unsigned short*)(ws + (38u << 20)); // 0.5 MB

  k_wprep<<<dim3(12, 4, 4), 256, 0, stream>>>(Wqkv, WqkvT, 256, 768);
  k_wprep<<<dim3(4, 4, 4), 256, 0, stream>>>(Wout, WoutT, 256, 256);
  k_proj<<<BT_, 256, 0, stream>>>(x, Wp, bp, pos, h, hbf);
  for (int l = 0; l < L_; ++l) {
    k_gemm_qkv<<<dim3(BT_ / 64, 12), 256, 0, stream>>>(
        hbf, WqkvT + l * 768 * 256, bqkv + l * 768, qb, kb, vt);
    k_attn<<<dim3(T_ / 16, B_ * H_), 128, 0, stream>>>(qb, kb, vt, ob);
    k_gemm_out<<<dim3(BT_ / 64, 4), 256, 0, stream>>>(
        ob, WoutT + l * 256 * 256, bout + l * 256, h, u);
    k_ln<<<BT_, 256, 0, stream>>>(u, ln_g + l * 256, ln_b + l * 256, h, hbf);
  }
  k_final<<<1, 64, 0, stream>>>(h, Wo, bo, (float*)d_out);
}

// Round 5
// 262.532 us; speedup vs baseline: 1.1974x; 1.1974x over previous
//
#include <hip/hip_runtime.h>
#include <hip/hip_bf16.h>

#define B_ 8
#define T_ 1024
#define IN_DIM_ 16
#define D_ 256
#define H_ 8
#define L_ 4
#define DK_ 32
#define BT_ (B_*T_)
#define LDT 72   // padded LDS stride for GEMM tiles (BK=64)

typedef __attribute__((ext_vector_type(8))) __bf16 bf16x8;
typedef __attribute__((ext_vector_type(8))) unsigned short u16x8;
typedef __attribute__((ext_vector_type(4))) unsigned short u16x4;
typedef __attribute__((ext_vector_type(4))) float f32x4;
typedef __attribute__((ext_vector_type(4))) unsigned int u32x4;

static __device__ __forceinline__ unsigned short f2bf(float f) {
  union { float f; unsigned int u; } c{f};
  unsigned int u = c.u;
  u += 0x7fff + ((u >> 16) & 1);
  return (unsigned short)(u >> 16);
}
static __device__ __forceinline__ bf16x8 as_bf(u16x8 v) {
  return __builtin_bit_cast(bf16x8, v);
}

// ---------------- weight prep: f32 [z][R][C] -> bf16 [z][C][R] ----------------
__global__ __launch_bounds__(256) void k_wprep(
    const float* __restrict__ in, unsigned short* __restrict__ out,
    int R, int C) {
  __shared__ float tile[64][65];
  const float* inz = in + (size_t)blockIdx.z * R * C;
  unsigned short* outz = out + (size_t)blockIdx.z * R * C;
  int r0 = blockIdx.y * 64, c0 = blockIdx.x * 64;
  int tid = threadIdx.x;
  int tr = tid >> 2, tc = (tid & 3) * 16;
  #pragma unroll
  for (int i = 0; i < 16; i += 4) {
    float4 v = *(const float4*)(inz + (r0 + tr) * C + c0 + tc + i);
    tile[tr][tc + i] = v.x; tile[tr][tc + i + 1] = v.y;
    tile[tr][tc + i + 2] = v.z; tile[tr][tc + i + 3] = v.w;
  }
  __syncthreads();
  #pragma unroll
  for (int i = 0; i < 16; ++i)
    outz[(c0 + tr) * R + r0 + tc + i] = f2bf(tile[tc + i][tr]);
}

// ---------------- input projection: h = x@Wp + bp + pos ----------------
__global__ __launch_bounds__(256) void k_proj(
    const float* __restrict__ x, const float* __restrict__ Wp,
    const float* __restrict__ bp, const float* __restrict__ pos,
    float* __restrict__ h, unsigned short* __restrict__ hbf) {
  int row = blockIdx.x;            // bt
  int c = threadIdx.x;             // 0..255
  int t = row & (T_ - 1);
  float acc = bp[c] + pos[t * D_ + c];
  const float* xr = x + row * IN_DIM_;
  #pragma unroll
  for (int k = 0; k < IN_DIM_; ++k) acc += xr[k] * Wp[k * D_ + c];
  h[row * D_ + c] = acc;
  hbf[row * D_ + c] = f2bf(acc);
}

// ---------------- QKV GEMM: (BTx256 bf16) x (768x256 bf16 W^T) ----------------
// q written PRE-SCALED by 1/sqrt(dk)*log2(e) -> attn does exp2(s) directly.
// q,k [b][h][t][dk]; v tiled-transposed [b][h][t/32][dk][32]
__global__ __launch_bounds__(256) void k_gemm_qkv(
    const unsigned short* __restrict__ A,    // BT x 256 bf16
    const unsigned short* __restrict__ Bt,   // 768 x 256 bf16 (W^T)
    const float* __restrict__ bias,          // 768
    unsigned short* __restrict__ qb, unsigned short* __restrict__ kb,
    unsigned short* __restrict__ vt) {
  __shared__ unsigned short As[64 * LDT];
  __shared__ unsigned short Bs[64 * LDT];
  int row0 = blockIdx.x * 64;
  int col0 = blockIdx.y * 64;
  int tid = threadIdx.x;
  int lane = tid & 63, w = tid >> 6;
  int g = lane >> 4, li = lane & 15;
  int wr = (w >> 1) * 32, wc = (w & 1) * 32;
  f32x4 acc[2][2] = {};
  for (int k0 = 0; k0 < 256; k0 += 64) {
    __syncthreads();
    int r = tid >> 2, kk = (tid & 3) * 16;
    *(u16x8*)(As + r * LDT + kk)     = *(const u16x8*)(A + (row0 + r) * 256 + k0 + kk);
    *(u16x8*)(As + r * LDT + kk + 8) = *(const u16x8*)(A + (row0 + r) * 256 + k0 + kk + 8);
    *(u16x8*)(Bs + r * LDT + kk)     = *(const u16x8*)(Bt + (col0 + r) * 256 + k0 + kk);
    *(u16x8*)(Bs + r * LDT + kk + 8) = *(const u16x8*)(Bt + (col0 + r) * 256 + k0 + kk + 8);
    __syncthreads();
    #pragma unroll
    for (int ks = 0; ks < 2; ++ks) {
      bf16x8 af[2], bfr[2];
      #pragma unroll
      for (int m = 0; m < 2; ++m)
        af[m] = as_bf(*(const u16x8*)(As + (wr + m * 16 + li) * LDT + ks * 32 + g * 8));
      #pragma unroll
      for (int n = 0; n < 2; ++n)
        bfr[n] = as_bf(*(const u16x8*)(Bs + (wc + n * 16 + li) * LDT + ks * 32 + g * 8));
      #pragma unroll
      for (int m = 0; m < 2; ++m)
        #pragma unroll
        for (int n = 0; n < 2; ++n)
          acc[m][n] = __builtin_amdgcn_mfma_f32_16x16x32_bf16(af[m], bfr[n], acc[m][n], 0, 0, 0);
    }
  }
  const float QSC = 0.25505654f;  // (1/sqrt(32)) * log2(e)
  #pragma unroll
  for (int m = 0; m < 2; ++m)
    #pragma unroll
    for (int n = 0; n < 2; ++n) {
      int c = col0 + wc + n * 16 + li;
      int rbase = row0 + wr + m * 16 + g * 4;
      int b = rbase >> 10, t = rbase & (T_ - 1);
      int s = c >> 8, rem = c & 255, hh = rem >> 5, dk = rem & 31;
      if (s == 0) {
        #pragma unroll
        for (int j = 0; j < 4; ++j) {
          float v = (acc[m][n][j] + bias[c]) * QSC;
          qb[(((b * H_ + hh) * T_) + t + j) * DK_ + dk] = f2bf(v);
        }
      } else if (s == 1) {
        #pragma unroll
        for (int j = 0; j < 4; ++j) {
          float v = acc[m][n][j] + bias[c];
          kb[(((b * H_ + hh) * T_) + t + j) * DK_ + dk] = f2bf(v);
        }
      } else {
        u16x4 pk;
        #pragma unroll
        for (int j = 0; j < 4; ++j) pk[j] = f2bf(acc[m][n][j] + bias[c]);
        // tiled V^T: [bh][t>>5][dk][t&31]
        *(u16x4*)(vt + (b * H_ + hh) * (DK_ * T_) +
                  ((t >> 5) * DK_ + dk) * 32 + (t & 31)) = pk;
      }
    }
}

// ---------------- attention: split-K flash, zero-LDS inner loop ----------------
// S^T via mfma(K,Q); P redistributed to A-fragment layout fully in-register via
// cvt_pk_bf16 + permlane32/16_swap (4x4 group transpose); V tiled for coalesced
// B-fragment loads. Partial (O,l) additive (no online max), combined via LDS.
__global__ __launch_bounds__(128) void k_attn(
    const unsigned short* __restrict__ qb, const unsigned short* __restrict__ kb,
    const unsigned short* __restrict__ vt, unsigned short* __restrict__ ob) {
  __shared__ float Osh[2][16][34];
  __shared__ float Lsh[2][16];
  int bh = blockIdx.y;
  int tid = threadIdx.x, lane = tid & 63, w = tid >> 6;  // w = k-half
  int g = lane >> 4, li = lane & 15;
  int q0 = blockIdx.x * 16;
  const unsigned short* Qp = qb + (bh * T_ + q0) * DK_;
  const unsigned short* Kp = kb + bh * T_ * DK_;
  const unsigned short* Vt = vt + bh * DK_ * T_;
  bf16x8 aq = as_bf(*(const u16x8*)(Qp + li * DK_ + g * 8));
  float l_run = 0.f;                         // lane-local partial denom (q = li)
  f32x4 oacc[2] = {};                        // O[q=g*4+j][dk=dh*16+li]
  for (int kt = w * 512; kt < (w + 1) * 512; kt += 32) {
    bf16x8 bk0 = as_bf(*(const u16x8*)(Kp + (kt + li) * DK_ + g * 8));
    bf16x8 bk1 = as_bf(*(const u16x8*)(Kp + (kt + 16 + li) * DK_ + g * 8));
    const unsigned short* vtile = Vt + (kt >> 5) * (DK_ * 32);
    bf16x8 bv0 = as_bf(*(const u16x8*)(vtile + li * 32 + g * 8));
    bf16x8 bv1 = as_bf(*(const u16x8*)(vtile + (16 + li) * 32 + g * 8));
    f32x4 s0 = {}, s1 = {};
    __builtin_amdgcn_s_setprio(1);
    // swapped: lane holds S[q=li][k=kt+g*4+j] (s0), +16 (s1); q pre-scaled
    s0 = __builtin_amdgcn_mfma_f32_16x16x32_bf16(bk0, aq, s0, 0, 0, 0);
    s1 = __builtin_amdgcn_mfma_f32_16x16x32_bf16(bk1, aq, s1, 0, 0, 0);
    __builtin_amdgcn_s_setprio(0);
    float p0[4], p1[4];
    #pragma unroll
    for (int j = 0; j < 4; ++j) {
      p0[j] = __builtin_amdgcn_exp2f(s0[j]);
      p1[j] = __builtin_amdgcn_exp2f(s1[j]);
    }
    l_run += ((p0[0] + p0[1]) + (p0[2] + p0[3])) +
             ((p1[0] + p1[1]) + (p1[2] + p1[3]));
    // pack P pairs: c0=(k4g,k4g+1) c1=(k4g+2,k4g+3) c2=(k16+4g,..) c3=(k16+4g+2,..)
    unsigned int c0, c1, c2, c3;
    asm("v_cvt_pk_bf16_f32 %0, %1, %2" : "=v"(c0) : "v"(p0[0]), "v"(p0[1]));
    asm("v_cvt_pk_bf16_f32 %0, %1, %2" : "=v"(c1) : "v"(p0[2]), "v"(p0[3]));
    asm("v_cvt_pk_bf16_f32 %0, %1, %2" : "=v"(c2) : "v"(p1[0]), "v"(p1[1]));
    asm("v_cvt_pk_bf16_f32 %0, %1, %2" : "=v"(c3) : "v"(p1[2]), "v"(p1[3]));
    // 4x4 group transpose: after stage1+stage2, lane(g,li) holds P[q=li][k=8g..8g+7]
    asm("v_permlane32_swap_b32 %0, %1" : "+v"(c0), "+v"(c2));
    asm("v_permlane32_swap_b32 %0, %1" : "+v"(c1), "+v"(c3));
    asm("v_permlane16_swap_b32 %0, %1" : "+v"(c0), "+v"(c2));
    asm("v_permlane16_swap_b32 %0, %1" : "+v"(c1), "+v"(c3));
    u32x4 paw; paw[0] = c0; paw[1] = c1; paw[2] = c2; paw[3] = c3;
    bf16x8 pa = __builtin_bit_cast(bf16x8, paw);
    __builtin_amdgcn_s_setprio(1);
    oacc[0] = __builtin_amdgcn_mfma_f32_16x16x32_bf16(pa, bv0, oacc[0], 0, 0, 0);
    oacc[1] = __builtin_amdgcn_mfma_f32_16x16x32_bf16(pa, bv1, oacc[1], 0, 0, 0);
    __builtin_amdgcn_s_setprio(0);
  }
  // reduce partial denominator across the 4 replicated groups
  l_run += __shfl_xor(l_run, 16);
  l_run += __shfl_xor(l_run, 32);
  // stash partials
  #pragma unroll
  for (int dh = 0; dh < 2; ++dh)
    #pragma unroll
    for (int j = 0; j < 4; ++j)
      Osh[w][g * 4 + j][dh * 16 + li] = oacc[dh][j];
  if (g == 0) Lsh[w][li] = l_run;
  __syncthreads();
  // combine halves; wave w writes dk-half w
  int b = bh >> 3, hh = bh & 7;
  #pragma unroll
  for (int j = 0; j < 4; ++j) {
    int q = g * 4 + j;
    int dk = w * 16 + li;
    float o = Osh[0][q][dk] + Osh[1][q][dk];
    float l = Lsh[0][q] + Lsh[1][q];
    ob[((b * T_ + q0 + q) * H_ + hh) * DK_ + dk] = f2bf(o / l);
  }
}

// ---------------- out-proj GEMM: o@Wout + bout + residual -> u (f32) ----------------
__global__ __launch_bounds__(256) void k_gemm_out(
    const unsigned short* __restrict__ A,    // BT x 256 bf16 (attn out)
    const unsigned short* __restrict__ Bt,   // 256 x 256 bf16 (W^T)
    const float* __restrict__ bias,          // 256
    const float* __restrict__ hres,          // BT x 256 f32 residual
    float* __restrict__ u) {
  __shared__ unsigned short As[64 * LDT];
  __shared__ unsigned short Bs[64 * LDT];
  int row0 = blockIdx.x * 64;
  int col0 = blockIdx.y * 64;
  int tid = threadIdx.x;
  int lane = tid & 63, w = tid >> 6;
  int g = lane >> 4, li = lane & 15;
  int wr = (w >> 1) * 32, wc = (w & 1) * 32;
  f32x4 acc[2][2] = {};
  for (int k0 = 0; k0 < 256; k0 += 64) {
    __syncthreads();
    int r = tid >> 2, kk = (tid & 3) * 16;
    *(u16x8*)(As + r * LDT + kk)     = *(const u16x8*)(A + (row0 + r) * 256 + k0 + kk);
    *(u16x8*)(As + r * LDT + kk + 8) = *(const u16x8*)(A + (row0 + r) * 256 + k0 + kk + 8);
    *(u16x8*)(Bs + r * LDT + kk)     = *(const u16x8*)(Bt + (col0 + r) * 256 + k0 + kk);
    *(u16x8*)(Bs + r * LDT + kk + 8) = *(const u16x8*)(Bt + (col0 + r) * 256 + k0 + kk + 8);
    __syncthreads();
    #pragma unroll
    for (int ks = 0; ks < 2; ++ks) {
      bf16x8 af[2], bfr[2];
      #pragma unroll
      for (int m = 0; m < 2; ++m)
        af[m] = as_bf(*(const u16x8*)(As + (wr + m * 16 + li) * LDT + ks * 32 + g * 8));
      #pragma unroll
      for (int n = 0; n < 2; ++n)
        bfr[n] = as_bf(*(const u16x8*)(Bs + (wc + n * 16 + li) * LDT + ks * 32 + g * 8));
      #pragma unroll
      for (int m = 0; m < 2; ++m)
        #pragma unroll
        for (int n = 0; n < 2; ++n)
          acc[m][n] = __builtin_amdgcn_mfma_f32_16x16x32_bf16(af[m], bfr[n], acc[m][n], 0, 0, 0);
    }
  }
  #pragma unroll
  for (int m = 0; m < 2; ++m)
    #pragma unroll
    for (int n = 0; n < 2; ++n)
      #pragma unroll
      for (int j = 0; j < 4; ++j) {
        int r = row0 + wr + m * 16 + g * 4 + j;
        int c = col0 + wc + n * 16 + li;
        u[r * 256 + c] = acc[m][n][j] + bias[c] + hres[r * 256 + c];
      }
}

// ---------------- layernorm: h = LN(u)*g + b; also bf16 mirror ----------------
__global__ __launch_bounds__(256) void k_ln(
    const float* __restrict__ u, const float* __restrict__ gg,
    const float* __restrict__ bb, float* __restrict__ h,
    unsigned short* __restrict__ hbf) {
  int row = blockIdx.x;
  int c = threadIdx.x;
  float v = u[row * D_ + c];
  float s = v, q = v * v;
  #pragma unroll
  for (int o = 1; o < 64; o <<= 1) { s += __shfl_xor(s, o); q += __shfl_xor(q, o); }
  __shared__ float ls[4], lq[4];
  int w = threadIdx.x >> 6;
  if ((threadIdx.x & 63) == 0) { ls[w] = s; lq[w] = q; }
  __syncthreads();
  s = ls[0] + ls[1] + ls[2] + ls[3];
  q = lq[0] + lq[1] + lq[2] + lq[3];
  float mean = s * (1.0f / D_);
  float var = q * (1.0f / D_) - mean * mean;
  float rstd = rsqrtf(var + 1e-5f);
  float y = (v - mean) * rstd * gg[c] + bb[c];
  h[row * D_ + c] = y;
  hbf[row * D_ + c] = f2bf(y);
}

// ---------------- final: out = h[:, -1, :] @ Wo + bo ----------------
__global__ void k_final(const float* __restrict__ h, const float* __restrict__ Wo,
                        const float* __restrict__ bo, float* __restrict__ out) {
  int tid = threadIdx.x;
  if (tid >= B_ * 3) return;
  int b = tid / 3, j = tid % 3;
  const float* hr = h + (b * T_ + (T_ - 1)) * D_;
  float acc = bo[j];
  for (int k = 0; k < D_; ++k) acc += hr[k] * Wo[k * 3 + j];
  out[tid] = acc;
}

extern "C" void kernel_launch(void* const* d_in, const int* in_sizes, int n_in,
                              void* d_out, int out_size, void* d_ws, size_t ws_size,
                              hipStream_t stream) {
  const float* x    = (const float*)d_in[0];
  const float* Wp   = (const float*)d_in[1];
  const float* bp   = (const float*)d_in[2];
  const float* pos  = (const float*)d_in[3];
  const float* Wqkv = (const float*)d_in[4];
  const float* bqkv = (const float*)d_in[5];
  const float* Wout = (const float*)d_in[6];
  const float* bout = (const float*)d_in[7];
  const float* ln_g = (const float*)d_in[8];
  const float* ln_b = (const float*)d_in[9];
  const float* Wo   = (const float*)d_in[10];
  const float* bo   = (const float*)d_in[11];

  char* ws = (char*)d_ws;
  float* h            = (float*)(ws);                        // 8 MB
  float* u            = (float*)(ws + (8u << 20));           // 8 MB
  unsigned short* hbf = (unsigned short*)(ws + (16u << 20)); // 4 MB
  unsigned short* qb  = (unsigned short*)(ws + (20u << 20)); // 4 MB
  unsigned short* kb  = (unsigned short*)(ws + (24u << 20)); // 4 MB
  unsigned short* vt  = (unsigned short*)(ws + (28u << 20)); // 4 MB (tiled V^T)
  unsigned short* ob  = (unsigned short*)(ws + (32u << 20)); // 4 MB
  unsigned short* WqkvT = (unsigned short*)(ws + (36u << 20)); // 1.5 MB
  unsigned short* WoutT = (unsigned short*)(ws + (38u << 20)); // 0.5 MB

  k_wprep<<<dim3(12, 4, 4), 256, 0, stream>>>(Wqkv, WqkvT, 256, 768);
  k_wprep<<<dim3(4, 4, 4), 256, 0, stream>>>(Wout, WoutT, 256, 256);
  k_proj<<<BT_, 256, 0, stream>>>(x, Wp, bp, pos, h, hbf);
  for (int l = 0; l < L_; ++l) {
    k_gemm_qkv<<<dim3(BT_ / 64, 12), 256, 0, stream>>>(
        hbf, WqkvT + l * 768 * 256, bqkv + l * 768, qb, kb, vt);
    k_attn<<<dim3(T_ / 16, B_ * H_), 128, 0, stream>>>(qb, kb, vt, ob);
    k_gemm_out<<<dim3(BT_ / 64, 4), 256, 0, stream>>>(
        ob, WoutT + l * 256 * 256, bout + l * 256, h, u);
    k_ln<<<BT_, 256, 0, stream>>>(u, ln_g + l * 256, ln_b + l * 256, h, hbf);
  }
  k_final<<<1, 64, 0, stream>>>(h, Wo, bo, (float*)d_out);
}